// Round 4
// 480.026 us; speedup vs baseline: 1.1113x; 1.1113x over previous
//
#include <hip/hip_runtime.h>

// Problem: B=4, C=64, H=128, W=416; corr 81 ch (dy,dx in [-4,4]); disp 192 ch (dx-96 in [-96,95])
// fp32 inputs/outputs; compute via bf16 MFMA (harness compares bf16-floored ref, thr=2% absmax).
//
// v3 (resubmit; round-3 failure was container-level — v2 ran fine in round 2, and v3 only adds
// wave-local fences, so it cannot be the crash cause).
// v3 = v2 + wave-level LDS ordering fences. v2's per-wave result staging (zero -> MFMA scatter
// -> copyout) communicates ACROSS LANES through LDS with no sync point; the compiler's
// per-thread alias analysis may legally reorder those ds ops (cross-lane LDS comms are ordered
// only by instruction order) -> full-magnitude wrong entries (absmax 41.9). Fix: at every
// cross-lane seam, asm "s_waitcnt lgkmcnt(0)" + "memory" clobber (pins compiler order AND
// completes all prior DS writes before subsequent reads; sufficient at wave scope) +
// sched_barrier(0). Design otherwise unchanged:
// (a) wave-private A-fragments in VGPRs (no As LDS), (b) XOR-swizzled stride-64 B tiles,
// (c) per-wave result staging -> no block barriers in MFMA phase, (d) disp d-chunking 2 halves,
// (e) corr Bs double-buffered. disp LDS 76KB, corr 59.9KB -> 2 blocks/CU, 4 waves/SIMD.
#define Wd 416
#define Hd 128
#define Cd 64
#define HWd 53248  // H*W

typedef __attribute__((ext_vector_type(8))) short short8;   // 8 bf16 MFMA fragment
typedef __attribute__((ext_vector_type(4))) float f32x4;    // MFMA accumulator

union frag8 { short8 s; unsigned int u[4]; };

__device__ __forceinline__ float bf2f(unsigned short u) {
    unsigned int v = ((unsigned int)u) << 16;
    return __builtin_bit_cast(float, v);
}
__device__ __forceinline__ unsigned short f2bf(float f) {
    unsigned int u = __builtin_bit_cast(unsigned int, f);
    u += 0x7fffu + ((u >> 16) & 1u);   // round-to-nearest-even
    return (unsigned short)(u >> 16);
}
__device__ __forceinline__ unsigned int pk2(float lo, float hi) {
    return (unsigned int)f2bf(lo) | ((unsigned int)f2bf(hi) << 16);
}
__device__ __forceinline__ float lrelu(float v) { return (v >= 0.f) ? v : 0.1f * v; }

// Wave-scope LDS fence: completes all prior DS writes and pins compiler ordering so
// cross-lane LDS producer->consumer within a wave is safe without a block barrier.
__device__ __forceinline__ void wave_fence() {
    asm volatile("s_waitcnt lgkmcnt(0)" ::: "memory");
    __builtin_amdgcn_sched_barrier(0);
}

// ---------------------------------------------------------------------------
// Kernel 1: bilinear warp of x2 (fp32) by flow (fp32) -> x2wT bf16 in ws,
// layout [b][y][x][c] (c contiguous). 8 threads/pixel, 8 channels each. (unchanged)
// ---------------------------------------------------------------------------
__global__ __launch_bounds__(256) void warp_k(const float* __restrict__ x2,
                                              const float* __restrict__ flow,
                                              unsigned short* __restrict__ x2wT) {
    int gid = blockIdx.x * 256 + threadIdx.x;   // 4*128*416*8 threads exactly
    int j = gid & 7;          // channel octet
    int p = gid >> 3;         // pixel id
    int x = p % Wd;
    int t = p / Wd;
    int y = t & 127;
    int b = t >> 7;

    int fbase = ((b * 2) * Hd + y) * Wd + x;
    float fx = flow[fbase];            // x-offset = channel 0
    float fy = flow[fbase + HWd];      // y-offset = channel 1
    float gx = (float)x + fx;
    float gy = (float)y + fy;
    float fx0 = floorf(gx), fy0 = floorf(gy);
    float wx = gx - fx0, wy = gy - fy0;
    int x0 = (int)fx0, y0 = (int)fy0;
    bool vx0 = (unsigned)x0 < (unsigned)Wd, vx1 = (unsigned)(x0 + 1) < (unsigned)Wd;
    bool vy0 = (unsigned)y0 < (unsigned)Hd, vy1 = (unsigned)(y0 + 1) < (unsigned)Hd;
    int cx0 = min(max(x0, 0), Wd - 1), cx1 = min(max(x0 + 1, 0), Wd - 1);
    int cy0 = min(max(y0, 0), Hd - 1), cy1 = min(max(y0 + 1, 0), Hd - 1);
    float w00 = (1.f - wx) * (1.f - wy) * ((vx0 && vy0) ? 1.f : 0.f);
    float w01 = wx * (1.f - wy) * ((vx1 && vy0) ? 1.f : 0.f);
    float w10 = (1.f - wx) * wy * ((vx0 && vy1) ? 1.f : 0.f);
    float w11 = wx * wy * ((vx1 && vy1) ? 1.f : 0.f);
    int o00 = cy0 * Wd + cx0, o01 = cy0 * Wd + cx1;
    int o10 = cy1 * Wd + cx0, o11 = cy1 * Wd + cx1;

    const float* base = x2 + (long)(b * Cd + j * 8) * HWd;
    unsigned int res[4];
#pragma unroll
    for (int cc = 0; cc < 8; cc++) {
        const float* pc = base + cc * HWd;
        float v = w00 * pc[o00] + w01 * pc[o01] + w10 * pc[o10] + w11 * pc[o11];
        unsigned short h = f2bf(v);
        if (cc & 1) res[cc >> 1] |= ((unsigned int)h) << 16;
        else        res[cc >> 1] = h;
    }
    *(uint4*)(x2wT + ((long)p * Cd + j * 8)) = make_uint4(res[0], res[1], res[2], res[3]);
}

// ---------------------------------------------------------------------------
// Kernel 2: disp corr volume (192 channels), one block per (b, y).
// P[x,x'] = sum_c x1[c,x] * r1[c,x'];  out ch 81+d at (y,x) = lrelu(P[x, x+d-96]).
// Wave wv owns row tiles i = wv+8t. A-frags live in VGPRs (no As LDS). Two d-half
// passes (d in [96h,96h+96), g = jj-i in [-6,0]/[0,6]); per-wave Ds with wave fences
// at zero->scatter->copyout seams. LDS 76KB -> 2 blk/CU.
// ---------------------------------------------------------------------------
__global__ __launch_bounds__(512, 4) void disp_k(const float* __restrict__ x1,
                                                 const float* __restrict__ r1,
                                                 float* __restrict__ out) {
    __shared__ unsigned short Bs[Wd * 64];      // [x'][oc^(x'&7)][8] bf16, 53248 B
    __shared__ unsigned short Ds[8][96 * 16];   // per-wave d-half result, 24576 B

    int tid = threadIdx.x;
    int lane = tid & 63;
    int wv = tid >> 6;          // 8 waves
    int m = lane & 15;          // MFMA row/col within tile
    int q = lane >> 4;          // quad

    int bid = blockIdx.x;       // 512 blocks = 4b * 128y
    int b = bid >> 7;
    int y = bid & 127;

    const float* Arow = x1 + ((long)(b * Cd) * Hd + y) * Wd;
    const float* Brow = r1 + ((long)(b * Cd) * Hd + y) * Wd;

    // stage r1 row transposed+swizzled. idx -> consecutive x per oc: coalesced dword loads,
    // b128 LDS writes. Swizzle: 16B-octet oc stored at oc^(x&7) -> frag reads 2-way (free).
    for (int idx = tid; idx < 8 * Wd; idx += 512) {     // 3328
        int x = idx % Wd;
        int oc = idx / Wd;
        const float* pb = Brow + (long)(oc * 8) * HWd + x;
        unsigned int wb[4];
#pragma unroll
        for (int e = 0; e < 4; e++)
            wb[e] = pk2(pb[(2 * e) * HWd], pb[(2 * e + 1) * HWd]);
        *(uint4*)&Bs[x * 64 + ((oc ^ (x & 7)) * 8)] = make_uint4(wb[0], wb[1], wb[2], wb[3]);
    }

    // A-fragments direct from global: lane(m,q) reads x = 16i+m, c = 8q+e (a0), 32+8q+e (a1).
    frag8 a0[4], a1[4];
#pragma unroll
    for (int t = 0; t < 4; t++) {
        int i = wv + 8 * t;
        if (i < 26) {
            const float* pa = Arow + 16 * i + m;
#pragma unroll
            for (int k = 0; k < 4; k++) {
                a0[t].u[k] = pk2(pa[(8 * q + 2 * k) * HWd], pa[(8 * q + 2 * k + 1) * HWd]);
                a1[t].u[k] = pk2(pa[(32 + 8 * q + 2 * k) * HWd], pa[(32 + 8 * q + 2 * k + 1) * HWd]);
            }
        }
    }
    __syncthreads();   // Bs staged (the only block-wide barrier in this kernel)

    unsigned short* Dw = Ds[wv];
#pragma unroll
    for (int h = 0; h < 2; h++) {          // d-half: d in [96h, 96h+96)
#pragma unroll
        for (int t = 0; t < 4; t++) {
            int i = wv + 8 * t;
            if (i >= 26) continue;
            // zero the per-wave half-tile (edge tiles leave zero-padded entries)
#pragma unroll
            for (int z = 0; z < 3; z++)
                *(uint4*)&Dw[(lane + 64 * z) * 8] = make_uint4(0, 0, 0, 0);
            wave_fence();    // zero visible to all lanes before scatter may overwrite
#pragma unroll
            for (int gg = 0; gg < 7; gg++) {
                int g = h ? gg : gg - 6;   // h=0: g in [-6,0]; h=1: g in [0,6]
                int jj = i + g;
                if ((unsigned)jj >= 26u) continue;
                int xp = 16 * jj + m;
                const unsigned short* bp = &Bs[xp * 64];
                short8 b0 = *(const short8*)(bp + ((q ^ (xp & 7)) * 8));
                short8 b1 = *(const short8*)(bp + (((q + 4) ^ (xp & 7)) * 8));
                f32x4 acc = {0.f, 0.f, 0.f, 0.f};
                acc = __builtin_amdgcn_mfma_f32_16x16x32_bf16(a0[t].s, b0, acc, 0, 0, 0);
                acc = __builtin_amdgcn_mfma_f32_16x16x32_bf16(a1[t].s, b1, acc, 0, 0, 0);
                // lane holds P[x = 16i+4q+r][x' = 16jj+m]; d = x'-x+96 - 96h
                int dbase = 16 * g + m - 4 * q + 96 - 96 * h;
#pragma unroll
                for (int r = 0; r < 4; r++) {
                    int d = dbase - r;
                    if ((unsigned)d < 96u)
                        Dw[d * 16 + 4 * q + r] = f2bf(lrelu(acc[r]));
                }
            }
            wave_fence();    // all lanes' scatters complete before cross-lane copyout reads
            // wave-private copyout: 96 d-rows x 16 x as float2
            long chb = ((long)(b * 273 + 81 + 96 * h) * Hd + y) * Wd + 16 * i;
#pragma unroll
            for (int k = 0; k < 12; k++) {
                int e = 64 * k + lane;     // dword index into Dw: d = e>>3, xpair = e&7
                unsigned int w = *(unsigned int*)&Dw[e * 2];
                int d = e >> 3, xx = (e & 7) * 2;
                *(float2*)(out + chb + (long)d * HWd + xx) =
                    make_float2(bf2f((unsigned short)(w & 0xffffu)),
                                bf2f((unsigned short)(w >> 16)));
            }
            wave_fence();    // copyout reads done before next tile's zeroing
        }
    }
}

// ---------------------------------------------------------------------------
// Kernel 3: 81-channel corr volume, one block per (b, y-pair, x-half).
// Wave wv owns yy = wv&1, it = (wv>>1)+4t. A-frags in VGPRs for all 10 x2w rows.
// Bs double-buffered (stage row yp+1 while computing row yp): 1 barrier/row.
// Per-wave Cs with wave fences at scatter->copyout seams. LDS 59.9KB -> 2 blk/CU.
// ---------------------------------------------------------------------------
__global__ __launch_bounds__(512, 4) void corr_k(const float* __restrict__ x1,
                                                 const unsigned short* __restrict__ x2wT,
                                                 float* __restrict__ out) {
    __shared__ unsigned short Bs[2][224 * 64];  // [pl][oc^(pl&7)][8] bf16, 2x28672 B
    __shared__ unsigned short Cs[8][160];       // per-wave 9 dx x 16 x

    int tid = threadIdx.x;
    int lane = tid & 63;
    int wv = tid >> 6;
    int m = lane & 15;
    int q = lane >> 4;

    int bid = blockIdx.x;        // 512 = 4b * 64y2 * 2xh
    int b = bid & 3;
    int y2 = (bid >> 2) & 63;
    int xh = bid >> 8;
    int y0 = y2 * 2;
    int xbase = xh * 208;

    int yy = wv & 1;             // wave-uniform row within the y-pair
    int it0 = wv >> 1;           // tiles it = it0 + 4t cover [0,13) across waves

    // A-fragments direct from global x1, held in VGPRs across all 10 yp iterations
    frag8 a0[4], a1[4];
#pragma unroll
    for (int t = 0; t < 4; t++) {
        int it = it0 + 4 * t;
        if (it < 13) {
            const float* pa = x1 + ((long)(b * Cd) * Hd + (y0 + yy)) * Wd + xbase + 16 * it + m;
#pragma unroll
            for (int k = 0; k < 4; k++) {
                a0[t].u[k] = pk2(pa[(8 * q + 2 * k) * HWd], pa[(8 * q + 2 * k + 1) * HWd]);
                a1[t].u[k] = pk2(pa[(32 + 8 * q + 2 * k) * HWd], pa[(32 + 8 * q + 2 * k + 1) * HWd]);
            }
        }
    }

    auto stage = [&](int yp, int sel) {
        int yg = y0 - 4 + yp;
        bool yok = (unsigned)yg < (unsigned)Hd;
        for (int idx = tid; idx < 224 * 8; idx += 512) {
            int pl = idx >> 3, oc = idx & 7;
            int xg = xbase - 4 + pl;
            uint4 v = make_uint4(0, 0, 0, 0);
            if (yok && (unsigned)xg < (unsigned)Wd)
                v = *(const uint4*)(x2wT + (((long)(b * Hd + yg) * Wd + xg) * Cd + oc * 8));
            *(uint4*)&Bs[sel][pl * 64 + ((oc ^ (pl & 7)) * 8)] = v;
        }
    };

    stage(0, 0);
    __syncthreads();

    for (int yp = 0; yp < 10; yp++) {        // x2w rows y0-4 .. y0+5
        int cur = yp & 1;
        if (yp < 9) stage(yp + 1, cur ^ 1);  // overlap next-row staging with compute
        int dy = yp - 4 - yy;
        if ((unsigned)(dy + 4) <= 8u) {
            long obase = ((long)(b * 273 + (dy + 4) * 9) * Hd + (y0 + yy)) * Wd + xbase;
#pragma unroll
            for (int t = 0; t < 4; t++) {
                int it = it0 + 4 * t;
                if (it >= 13) continue;
#pragma unroll
                for (int dj = 0; dj < 2; dj++) {
                    int pl = 16 * (it + dj) + m;
                    const unsigned short* bp = &Bs[cur][pl * 64];
                    short8 b0 = *(const short8*)(bp + ((q ^ (pl & 7)) * 8));
                    short8 b1 = *(const short8*)(bp + (((q + 4) ^ (pl & 7)) * 8));
                    f32x4 acc = {0.f, 0.f, 0.f, 0.f};
                    acc = __builtin_amdgcn_mfma_f32_16x16x32_bf16(a0[t].s, b0, acc, 0, 0, 0);
                    acc = __builtin_amdgcn_mfma_f32_16x16x32_bf16(a1[t].s, b1, acc, 0, 0, 0);
                    // lane holds P[xl = 16it+4q+r][pl = 16jt+m]; dx+4 = pl - xl
                    int dbase = 16 * dj + m - 4 * q;
#pragma unroll
                    for (int r = 0; r < 4; r++) {
                        int dx4 = dbase - r;
                        if ((unsigned)dx4 <= 8u)
                            Cs[wv][dx4 * 16 + 4 * q + r] = f2bf(lrelu(acc[r]));
                    }
                }
                wave_fence();   // all lanes' scatters complete before cross-lane copyout reads
                // wave-private copyout: 9 dx-rows x 16 x (72 dwords) as float2
#pragma unroll
                for (int k = 0; k < 2; k++) {
                    int e = 64 * k + lane;
                    if (e < 72) {
                        unsigned int w = *(unsigned int*)&Cs[wv][e * 2];
                        int dxr = e >> 3, xx = (e & 7) * 2;
                        *(float2*)(out + obase + (long)dxr * HWd + 16 * it + xx) =
                            make_float2(bf2f((unsigned short)(w & 0xffffu)),
                                        bf2f((unsigned short)(w >> 16)));
                    }
                }
                wave_fence();   // copyout reads done before next tile's scatter
            }
        }
        __syncthreads();   // readers of buf[cur] done; buf[cur] safe to restage at yp+2
    }
}

extern "C" void kernel_launch(void* const* d_in, const int* in_sizes, int n_in,
                              void* d_out, int out_size, void* d_ws, size_t ws_size,
                              hipStream_t stream) {
    const float* x1 = (const float*)d_in[0];
    const float* x2 = (const float*)d_in[1];
    const float* r1 = (const float*)d_in[2];
    const float* fl = (const float*)d_in[3];
    float* out = (float*)d_out;
    unsigned short* x2wT = (unsigned short*)d_ws;   // 4*128*416*64 bf16 = 27.3 MB

    warp_k<<<6656, 256, 0, stream>>>(x2, fl, x2wT);        // 4*128*416*8/256
    disp_k<<<512, 512, 0, stream>>>(x1, r1, out);
    corr_k<<<512, 512, 0, stream>>>(x1, x2wT, out);
}

// Round 5
// 456.815 us; speedup vs baseline: 1.1678x; 1.0508x over previous
//
#include <hip/hip_runtime.h>

// Problem: B=4, C=64, H=128, W=416; corr 81 ch (dy,dx in [-4,4]); disp 192 ch (dx-96 in [-96,95])
// fp32 inputs/outputs; compute via bf16 MFMA (harness compares bf16-floored ref, thr=2% absmax).
//
// v4 = v3 + three changes:
// (1) warp_k relayout: lanes span consecutive x of ONE channel octet (gathers ~2-4 lines/instr
//     instead of 64); x2wT becomes octet-major [b][oc][y][x][8ch] so writes stay coalesced.
//     corr stage re-indexed (oc=idx/224, pl=idx%224) -> reads of new layout contiguous.
// (2) disp_k+corr_k fused into one 1024-block kernel (parity-interleaved): removes launch
//     boundary + tail (512 blocks = exactly 2/CU, slowest block stalled the next kernel).
//     LDS union 76KB -> still 2 blocks/CU for both paths.
// (3) disp interior tiles (h=0: i>=6; h=1: i<=19) skip Ds zero+fence: every (d,xcol) cell is
//     written exactly once by a unique (g,m) [m=(d+xcol-96+96h) mod 16, g unique in range], so
//     no stale data. Saves a full lgkmcnt(0) drain for 40/52 tile-passes.
// v3's wave fences retained at every cross-lane LDS seam (verified fail->pass in r2->r4).
#define Wd 416
#define Hd 128
#define Cd 64
#define HWd 53248  // H*W

typedef __attribute__((ext_vector_type(8))) short short8;   // 8 bf16 MFMA fragment
typedef __attribute__((ext_vector_type(4))) float f32x4;    // MFMA accumulator

union frag8 { short8 s; unsigned int u[4]; };

__device__ __forceinline__ float bf2f(unsigned short u) {
    unsigned int v = ((unsigned int)u) << 16;
    return __builtin_bit_cast(float, v);
}
__device__ __forceinline__ unsigned short f2bf(float f) {
    unsigned int u = __builtin_bit_cast(unsigned int, f);
    u += 0x7fffu + ((u >> 16) & 1u);   // round-to-nearest-even
    return (unsigned short)(u >> 16);
}
__device__ __forceinline__ unsigned int pk2(float lo, float hi) {
    return (unsigned int)f2bf(lo) | ((unsigned int)f2bf(hi) << 16);
}
__device__ __forceinline__ float lrelu(float v) { return (v >= 0.f) ? v : 0.1f * v; }

// Wave-scope LDS fence: completes all prior DS writes and pins compiler ordering so
// cross-lane LDS producer->consumer within a wave is safe without a block barrier.
__device__ __forceinline__ void wave_fence() {
    asm volatile("s_waitcnt lgkmcnt(0)" ::: "memory");
    __builtin_amdgcn_sched_barrier(0);
}

// ---------------------------------------------------------------------------
// Kernel 1: bilinear warp of x2 -> x2wT bf16, octet-major layout
// [b][oc][y][x][8ch]: element (b,oc,y,x,c) at (((b*8+oc)*Hd+y)*Wd+x)*8 + c.
// One thread = one (b,oc,y,x): 8 channels. Lanes span consecutive x -> the 32
// neighbor-gathers are line-coalesced (jittered only by flow); uint4 writes at
// idx*8 shorts are perfectly coalesced (16B/lane consecutive).
// ---------------------------------------------------------------------------
__global__ __launch_bounds__(256) void warp_k(const float* __restrict__ x2,
                                              const float* __restrict__ flow,
                                              unsigned short* __restrict__ x2wT) {
    int idx = blockIdx.x * 256 + threadIdx.x;   // 4*8*128*416 threads exactly
    int x = idx % Wd;
    int r = idx / Wd;         // (b*8+oc)*128 + y
    int y = r & 127;
    int s = r >> 7;
    int oc = s & 7;
    int b = s >> 3;

    int fbase = ((b * 2) * Hd + y) * Wd + x;
    float fx = flow[fbase];            // x-offset = channel 0
    float fy = flow[fbase + HWd];      // y-offset = channel 1
    float gx = (float)x + fx;
    float gy = (float)y + fy;
    float fx0 = floorf(gx), fy0 = floorf(gy);
    float wx = gx - fx0, wy = gy - fy0;
    int x0 = (int)fx0, y0 = (int)fy0;
    bool vx0 = (unsigned)x0 < (unsigned)Wd, vx1 = (unsigned)(x0 + 1) < (unsigned)Wd;
    bool vy0 = (unsigned)y0 < (unsigned)Hd, vy1 = (unsigned)(y0 + 1) < (unsigned)Hd;
    int cx0 = min(max(x0, 0), Wd - 1), cx1 = min(max(x0 + 1, 0), Wd - 1);
    int cy0 = min(max(y0, 0), Hd - 1), cy1 = min(max(y0 + 1, 0), Hd - 1);
    float w00 = (1.f - wx) * (1.f - wy) * ((vx0 && vy0) ? 1.f : 0.f);
    float w01 = wx * (1.f - wy) * ((vx1 && vy0) ? 1.f : 0.f);
    float w10 = (1.f - wx) * wy * ((vx0 && vy1) ? 1.f : 0.f);
    float w11 = wx * wy * ((vx1 && vy1) ? 1.f : 0.f);
    int o00 = cy0 * Wd + cx0, o01 = cy0 * Wd + cx1;
    int o10 = cy1 * Wd + cx0, o11 = cy1 * Wd + cx1;

    const float* base = x2 + (long)(b * Cd + oc * 8) * HWd;
    unsigned int res[4];
#pragma unroll
    for (int cc = 0; cc < 8; cc++) {
        const float* pc = base + cc * HWd;
        float v = w00 * pc[o00] + w01 * pc[o01] + w10 * pc[o10] + w11 * pc[o11];
        unsigned short h = f2bf(v);
        if (cc & 1) res[cc >> 1] |= ((unsigned int)h) << 16;
        else        res[cc >> 1] = h;
    }
    *(uint4*)(x2wT + ((long)idx * 8)) = make_uint4(res[0], res[1], res[2], res[3]);
}

// ---------------------------------------------------------------------------
// Fused kernel: parity-interleaved disp (even blocks) / corr (odd blocks).
// LDS is a union of the two layouts: max 77824 B -> 2 blocks/CU.
// ---------------------------------------------------------------------------
struct DispSmem {
    unsigned short Bs[Wd * 64];     // [x'][oc^(x'&7)][8] bf16, 53248 B
    unsigned short Ds[8][96 * 16];  // per-wave d-half result, 24576 B
};
struct CorrSmem {
    unsigned short Bs[2][224 * 64]; // [pl][oc^(pl&7)][8] bf16, 2x28672 B
    unsigned short Cs[8][160];      // per-wave 9 dx x 16 x
};
union FusedSmem { DispSmem d; CorrSmem c; };

// ---- disp: one virtual block per (b, y) -----------------------------------
// P[x,x'] = sum_c x1[c,x] * r1[c,x'];  out ch 81+d at (y,x) = lrelu(P[x, x+d-96]).
__device__ __forceinline__ void disp_body(int bid, DispSmem& S,
                                          const float* __restrict__ x1,
                                          const float* __restrict__ r1,
                                          float* __restrict__ out) {
    int tid = threadIdx.x;
    int lane = tid & 63;
    int wv = tid >> 6;          // 8 waves
    int m = lane & 15;          // MFMA row/col within tile
    int q = lane >> 4;          // quad

    int b = bid >> 7;           // 512 virtual blocks = 4b * 128y
    int y = bid & 127;

    const float* Arow = x1 + ((long)(b * Cd) * Hd + y) * Wd;
    const float* Brow = r1 + ((long)(b * Cd) * Hd + y) * Wd;

    // stage r1 row transposed+swizzled: coalesced dword loads, conflict-free b128 writes.
    for (int idx = tid; idx < 8 * Wd; idx += 512) {     // 3328
        int x = idx % Wd;
        int oc = idx / Wd;
        const float* pb = Brow + (long)(oc * 8) * HWd + x;
        unsigned int wb[4];
#pragma unroll
        for (int e = 0; e < 4; e++)
            wb[e] = pk2(pb[(2 * e) * HWd], pb[(2 * e + 1) * HWd]);
        *(uint4*)&S.Bs[x * 64 + ((oc ^ (x & 7)) * 8)] = make_uint4(wb[0], wb[1], wb[2], wb[3]);
    }

    // A-fragments direct from global: lane(m,q) reads x = 16i+m, c = 8q+e (a0), 32+8q+e (a1).
    frag8 a0[4], a1[4];
#pragma unroll
    for (int t = 0; t < 4; t++) {
        int i = wv + 8 * t;
        if (i < 26) {
            const float* pa = Arow + 16 * i + m;
#pragma unroll
            for (int k = 0; k < 4; k++) {
                a0[t].u[k] = pk2(pa[(8 * q + 2 * k) * HWd], pa[(8 * q + 2 * k + 1) * HWd]);
                a1[t].u[k] = pk2(pa[(32 + 8 * q + 2 * k) * HWd], pa[(32 + 8 * q + 2 * k + 1) * HWd]);
            }
        }
    }
    __syncthreads();   // Bs staged (the only block-wide barrier in disp)

    unsigned short* Dw = S.Ds[wv];
#pragma unroll
    for (int h = 0; h < 2; h++) {          // d-half: d in [96h, 96h+96)
#pragma unroll
        for (int t = 0; t < 4; t++) {
            int i = wv + 8 * t;
            if (i >= 26) continue;
            // interior tiles have full (d,xcol) coverage (unique (g,m) per cell) -> skip zero
            bool interior = h ? (i <= 19) : (i >= 6);
            if (!interior) {
#pragma unroll
                for (int z = 0; z < 3; z++)
                    *(uint4*)&Dw[(lane + 64 * z) * 8] = make_uint4(0, 0, 0, 0);
                wave_fence();    // zero complete before scatter may overwrite
            }
#pragma unroll
            for (int gg = 0; gg < 7; gg++) {
                int g = h ? gg : gg - 6;   // h=0: g in [-6,0]; h=1: g in [0,6]
                int jj = i + g;
                if ((unsigned)jj >= 26u) continue;
                int xp = 16 * jj + m;
                const unsigned short* bp = &S.Bs[xp * 64];
                short8 b0 = *(const short8*)(bp + ((q ^ (xp & 7)) * 8));
                short8 b1 = *(const short8*)(bp + (((q + 4) ^ (xp & 7)) * 8));
                f32x4 acc = {0.f, 0.f, 0.f, 0.f};
                acc = __builtin_amdgcn_mfma_f32_16x16x32_bf16(a0[t].s, b0, acc, 0, 0, 0);
                acc = __builtin_amdgcn_mfma_f32_16x16x32_bf16(a1[t].s, b1, acc, 0, 0, 0);
                // lane holds P[x = 16i+4q+r][x' = 16jj+m]; d = x'-x+96 - 96h
                int dbase = 16 * g + m - 4 * q + 96 - 96 * h;
#pragma unroll
                for (int r = 0; r < 4; r++) {
                    int d = dbase - r;
                    if ((unsigned)d < 96u)
                        Dw[d * 16 + 4 * q + r] = f2bf(lrelu(acc[r]));
                }
            }
            wave_fence();    // all lanes' scatters complete before cross-lane copyout reads
            // wave-private copyout: 96 d-rows x 16 x as float2
            long chb = ((long)(b * 273 + 81 + 96 * h) * Hd + y) * Wd + 16 * i;
#pragma unroll
            for (int k = 0; k < 12; k++) {
                int e = 64 * k + lane;     // dword index into Dw: d = e>>3, xpair = e&7
                unsigned int w = *(unsigned int*)&Dw[e * 2];
                int d = e >> 3, xx = (e & 7) * 2;
                *(float2*)(out + chb + (long)d * HWd + xx) =
                    make_float2(bf2f((unsigned short)(w & 0xffffu)),
                                bf2f((unsigned short)(w >> 16)));
            }
            wave_fence();    // copyout reads done before next tile's scatter
        }
    }
}

// ---- corr: one virtual block per (b, y-pair, x-half) -----------------------
__device__ __forceinline__ void corr_body(int bid, CorrSmem& S,
                                          const float* __restrict__ x1,
                                          const unsigned short* __restrict__ x2wT,
                                          float* __restrict__ out) {
    int tid = threadIdx.x;
    int lane = tid & 63;
    int wv = tid >> 6;
    int m = lane & 15;
    int q = lane >> 4;

    int b = bid & 3;             // 512 virtual blocks = 4b * 64y2 * 2xh
    int y2 = (bid >> 2) & 63;
    int xh = bid >> 8;
    int y0 = y2 * 2;
    int xbase = xh * 208;

    int yy = wv & 1;             // wave-uniform row within the y-pair
    int it0 = wv >> 1;           // tiles it = it0 + 4t cover [0,13) across waves

    // A-fragments direct from global x1, held in VGPRs across all 10 yp iterations
    frag8 a0[4], a1[4];
#pragma unroll
    for (int t = 0; t < 4; t++) {
        int it = it0 + 4 * t;
        if (it < 13) {
            const float* pa = x1 + ((long)(b * Cd) * Hd + (y0 + yy)) * Wd + xbase + 16 * it + m;
#pragma unroll
            for (int k = 0; k < 4; k++) {
                a0[t].u[k] = pk2(pa[(8 * q + 2 * k) * HWd], pa[(8 * q + 2 * k + 1) * HWd]);
                a1[t].u[k] = pk2(pa[(32 + 8 * q + 2 * k) * HWd], pa[(32 + 8 * q + 2 * k + 1) * HWd]);
            }
        }
    }

    auto stage = [&](int yp, int sel) {
        int yg = y0 - 4 + yp;
        bool yok = (unsigned)yg < (unsigned)Hd;
        // oc-major loop: consecutive lanes -> consecutive pl of one octet -> contiguous reads
        for (int idx = tid; idx < 8 * 224; idx += 512) {
            int oc = idx / 224, pl = idx - oc * 224;
            int xg = xbase - 4 + pl;
            uint4 v = make_uint4(0, 0, 0, 0);
            if (yok && (unsigned)xg < (unsigned)Wd)
                v = *(const uint4*)(x2wT + ((((long)(b * 8 + oc) * Hd + yg) * Wd + xg) * 8));
            *(uint4*)&S.Bs[sel][pl * 64 + ((oc ^ (pl & 7)) * 8)] = v;
        }
    };

    stage(0, 0);
    __syncthreads();

    for (int yp = 0; yp < 10; yp++) {        // x2w rows y0-4 .. y0+5
        int cur = yp & 1;
        if (yp < 9) stage(yp + 1, cur ^ 1);  // overlap next-row staging with compute
        int dy = yp - 4 - yy;
        if ((unsigned)(dy + 4) <= 8u) {
            long obase = ((long)(b * 273 + (dy + 4) * 9) * Hd + (y0 + yy)) * Wd + xbase;
#pragma unroll
            for (int t = 0; t < 4; t++) {
                int it = it0 + 4 * t;
                if (it >= 13) continue;
#pragma unroll
                for (int dj = 0; dj < 2; dj++) {
                    int pl = 16 * (it + dj) + m;
                    const unsigned short* bp = &S.Bs[cur][pl * 64];
                    short8 b0 = *(const short8*)(bp + ((q ^ (pl & 7)) * 8));
                    short8 b1 = *(const short8*)(bp + (((q + 4) ^ (pl & 7)) * 8));
                    f32x4 acc = {0.f, 0.f, 0.f, 0.f};
                    acc = __builtin_amdgcn_mfma_f32_16x16x32_bf16(a0[t].s, b0, acc, 0, 0, 0);
                    acc = __builtin_amdgcn_mfma_f32_16x16x32_bf16(a1[t].s, b1, acc, 0, 0, 0);
                    // lane holds P[xl = 16it+4q+r][pl = 16jt+m]; dx+4 = pl - xl
                    int dbase = 16 * dj + m - 4 * q;
#pragma unroll
                    for (int r = 0; r < 4; r++) {
                        int dx4 = dbase - r;
                        if ((unsigned)dx4 <= 8u)
                            S.Cs[wv][dx4 * 16 + 4 * q + r] = f2bf(lrelu(acc[r]));
                    }
                }
                wave_fence();   // all lanes' scatters complete before cross-lane copyout reads
                // wave-private copyout: 9 dx-rows x 16 x (72 dwords) as float2
#pragma unroll
                for (int k = 0; k < 2; k++) {
                    int e = 64 * k + lane;
                    if (e < 72) {
                        unsigned int w = *(unsigned int*)&S.Cs[wv][e * 2];
                        int dxr = e >> 3, xx = (e & 7) * 2;
                        *(float2*)(out + obase + (long)dxr * HWd + 16 * it + xx) =
                            make_float2(bf2f((unsigned short)(w & 0xffffu)),
                                        bf2f((unsigned short)(w >> 16)));
                    }
                }
                wave_fence();   // copyout reads done before next tile's scatter
            }
        }
        __syncthreads();   // readers of buf[cur] done; buf[cur] safe to restage at yp+2
    }
}

__global__ __launch_bounds__(512, 4) void fused_k(const float* __restrict__ x1,
                                                  const float* __restrict__ r1,
                                                  const unsigned short* __restrict__ x2wT,
                                                  float* __restrict__ out) {
    __shared__ FusedSmem sm;
    int bid = blockIdx.x;       // 1024 blocks, parity-interleaved
    if ((bid & 1) == 0) disp_body(bid >> 1, sm.d, x1, r1, out);
    else                corr_body(bid >> 1, sm.c, x1, x2wT, out);
}

extern "C" void kernel_launch(void* const* d_in, const int* in_sizes, int n_in,
                              void* d_out, int out_size, void* d_ws, size_t ws_size,
                              hipStream_t stream) {
    const float* x1 = (const float*)d_in[0];
    const float* x2 = (const float*)d_in[1];
    const float* r1 = (const float*)d_in[2];
    const float* fl = (const float*)d_in[3];
    float* out = (float*)d_out;
    unsigned short* x2wT = (unsigned short*)d_ws;   // 4*8*128*416*8 bf16 = 27.3 MB

    warp_k<<<6656, 256, 0, stream>>>(x2, fl, x2wT);        // 4*8*128*416/256
    fused_k<<<1024, 512, 0, stream>>>(x1, r1, x2wT, out);
}